// Round 9
// baseline (206.797 us; speedup 1.0000x reference)
//
#include <hip/hip_runtime.h>

// Embedding: out[t, :] = W[:, x[t]] + b   (W [256,100000] row-major f32)
//
// Round 9: async direct-to-LDS staging. Evidence r2-r8: every cold-W kernel
// sits at ~2.8-3.4 TB/s regardless of read granule (64B/128B/1KB), occupancy
// (16-76%), and store flavor (NT vs plain) -- but L3-warm reads run 4.6 TB/s
// and write-only runs 6.8. Model: sync staging (load->LDS-store interleave)
// keeps only ~4 float4/wave in flight; 4KB / 900cyc HBM latency = 4.5 B/cyc/CU
// = 2.8 TB/s chip-wide == the wall. Fix: global_load_lds width=16 issued 16x
// back-to-back per wave (16KB in flight), no VGPR round-trip.
// Geometry (r6): bin = 256 vocab cols x 64 e-rows, grid (391 x 4).
//   k1: bucket tokens by bin = v>>8 (entry t | c<<16), CAP 256 (mean 168).
//   k2: stage 64 rows x 1KB via async DMA -> LDS [e][c] stride 257; scatter:
//       one wave per token writes out[t][g*64..+63] (256B plain store) + bias.
//   k3: overflow cleanup (P(bin>256) ~ 1e-10; never taken).

#define VOCAB 100000
#define EMBED 256
#define NTOK  (32 * 2048)
#define TILEC 256                              // vocab cols per bin
#define NBIN  ((VOCAB + TILEC - 1) / TILEC)    // 391 (last bin 160 cols)
#define NEG   4                                // e-groups of 64 rows
#define EROWS 64
#define CAP   256                              // slots per bin (mean 168)
#define LSTRIDE 257                            // LDS row stride (odd -> conflict-free)

// workspace ints: cnt [512) | list [NBIN*CAP) | flags [NTOK)
#define WS_CNT_OFF   0
#define WS_LIST_OFF  512
#define WS_FLAG_OFF  (WS_LIST_OFF + NBIN * CAP)
#define WS_INTS      (WS_FLAG_OFF + NTOK)

__global__ __launch_bounds__(256) void k1_bucket(
    const int* __restrict__ x,
    int* __restrict__ cnt,
    int* __restrict__ list,
    int* __restrict__ flags)
{
    int t4 = (blockIdx.x * 256 + threadIdx.x) * 4;
    if (t4 >= NTOK) return;
    const int4 v4 = *reinterpret_cast<const int4*>(x + t4);
    #pragma unroll
    for (int j = 0; j < 4; ++j) {
        const int v   = (&v4.x)[j];
        const int t   = t4 + j;
        const int bin = v >> 8;
        const int c   = v & (TILEC - 1);
        const int pos = atomicAdd(&cnt[bin], 1);
        const int ovf = (pos >= CAP);
        if (!ovf) list[bin * CAP + pos] = t | (c << 16);
        flags[t] = ovf;            // written for ALL t (ws is poisoned)
    }
}

__global__ __launch_bounds__(256) void k2_scatter(
    const float* __restrict__ W,
    const float* __restrict__ bias,
    const int* __restrict__ cnt,
    const int* __restrict__ list,
    float* __restrict__ out)
{
    __shared__ float tileT[EROWS * LSTRIDE];   // [e_local][c]
    __shared__ int   slist[CAP];

    const int bin  = blockIdx.x;
    const int g    = blockIdx.y;               // e rows g*64 .. g*64+63
    const int v0   = bin << 8;
    const int cols = (VOCAB - v0 < TILEC) ? (VOCAB - v0) : TILEC;
    const int t    = threadIdx.x;
    const int lane = t & 63;
    const int wave = t >> 6;

    slist[t] = list[bin * CAP + t];            // 1 KB coalesced prefetch

    const int c4 = lane << 2;                  // this lane's 16B column chunk
#if __has_builtin(__builtin_amdgcn_global_load_lds)
    // async staging: 16 DMAs per wave, back-to-back, nothing blocks until the
    // barrier. Lane l's 16B land at LDS base + l*16 -> row-major [e][c], c=l*4.
    if (c4 < cols) {
        #pragma unroll
        for (int j = 0; j < 16; ++j) {
            const int r = j * 4 + wave;        // e_local 0..63, wave-uniform
            const float* gp = W + (size_t)(g * EROWS + r) * VOCAB + v0 + c4;
            float* lp = &tileT[r * LSTRIDE];   // wave-uniform LDS base
            __builtin_amdgcn_global_load_lds(
                (const __attribute__((address_space(1))) void*)gp,
                (__attribute__((address_space(3))) void*)lp,
                16, 0, 0);
        }
    }
#else
    // sync fallback (r6-style)
    #pragma unroll
    for (int j = 0; j < 16; ++j) {
        const int r = j * 4 + wave;
        if (c4 < cols) {
            const float4 w = *reinterpret_cast<const float4*>(
                W + (size_t)(g * EROWS + r) * VOCAB + v0 + c4);
            tileT[r * LSTRIDE + c4 + 0] = w.x;
            tileT[r * LSTRIDE + c4 + 1] = w.y;
            tileT[r * LSTRIDE + c4 + 2] = w.z;
            tileT[r * LSTRIDE + c4 + 3] = w.w;
        }
    }
#endif
    __syncthreads();   // compiler emits s_waitcnt vmcnt(0) lgkmcnt(0) here

    int n = cnt[bin];                          // wave-uniform scalar load
    if (n > CAP) n = CAP;

    const float bv = bias[g * EROWS + lane];

    // one wave per token: lane = e_local reads LDS column c
    // (bank (lane*257+c)%32 = (lane+c)%32 -> 2-way over 64 lanes = free),
    // writes 256 B contiguous per wave, plain store.
    for (int k = wave; k < n; k += 4) {
        const int packed = slist[k];
        const int tok = packed & 0xFFFF;
        const int c   = packed >> 16;
        out[(size_t)tok * EMBED + g * EROWS + lane] = tileT[lane * LSTRIDE + c] + bv;
    }
}

__global__ __launch_bounds__(256) void k3_cleanup(
    const int* __restrict__ x,
    const float* __restrict__ W,
    const float* __restrict__ bias,
    const int* __restrict__ flags,
    float* __restrict__ out)
{
    int t = blockIdx.x * 256 + threadIdx.x;
    if (t >= NTOK) return;
    if (!flags[t]) return;              // never taken for this input
    int v = x[t];
    for (int e = 0; e < EMBED; ++e)
        out[(size_t)t * EMBED + e] = W[(size_t)e * VOCAB + v] + bias[e];
}

// fallback: direct column gather, if ws too small
__global__ __launch_bounds__(256) void embed_gather_direct(
    const int* __restrict__ x,
    const float* __restrict__ W,
    const float* __restrict__ bias,
    float* __restrict__ out)
{
    const int tid   = blockIdx.x * blockDim.x + threadIdx.x;
    const int token = tid >> 6;
    const int e     = (tid & 63) << 2;
    if (token >= NTOK) return;
    const int v = x[token];
    const float4 bv = *reinterpret_cast<const float4*>(bias + e);
    float4 r;
    r.x = W[(size_t)(e + 0) * VOCAB + v] + bv.x;
    r.y = W[(size_t)(e + 1) * VOCAB + v] + bv.y;
    r.z = W[(size_t)(e + 2) * VOCAB + v] + bv.z;
    r.w = W[(size_t)(e + 3) * VOCAB + v] + bv.w;
    *reinterpret_cast<float4*>(out + (size_t)token * EMBED + e) = r;
}

extern "C" void kernel_launch(void* const* d_in, const int* in_sizes, int n_in,
                              void* d_out, int out_size, void* d_ws, size_t ws_size,
                              hipStream_t stream)
{
    const int*   x = (const int*)d_in[0];
    const float* W = (const float*)d_in[1];
    const float* b = (const float*)d_in[2];
    float*     out = (float*)d_out;

    if (ws_size >= (size_t)WS_INTS * sizeof(int)) {
        int* ws    = (int*)d_ws;
        int* cnt   = ws + WS_CNT_OFF;
        int* list  = ws + WS_LIST_OFF;
        int* flags = ws + WS_FLAG_OFF;

        hipMemsetAsync(cnt, 0, NBIN * sizeof(int), stream);
        k1_bucket <<<NTOK / 4 / 256, 256, 0, stream>>>(x, cnt, list, flags);
        dim3 g2(NBIN, NEG);
        k2_scatter<<<g2,             256, 0, stream>>>(W, b, cnt, list, out);
        k3_cleanup<<<NTOK / 256,     256, 0, stream>>>(x, W, b, flags, out);
    } else {
        embed_gather_direct<<<NTOK * 64 / 256, 256, 0, stream>>>(x, W, b, out);
    }
}

// Round 10
// 189.942 us; speedup vs baseline: 1.0887x; 1.0887x over previous
//
#include <hip/hip_runtime.h>

// Embedding: out[t, :] = W[:, x[t]] + b   (W [256,100000] row-major f32)
//
// Round 10: BARRIER-FREE wave-private k2. Evidence r2-r9: cold-W pass pinned
// at 2.8-3.4 TB/s under every granule/occupancy/store-flavor/staging-depth
// variant -- all shared one trait: waves coupled via __syncthreads. Last
// mechanism: each wave owns one 16-col bin solo (16 float4 regs -> private
// LDS region -> scatter), zero barriers, 8 independent pipelined waves/CU.
// Token list in registers (CAP=64: slot k in lane k, __shfl broadcast).
// Aux trim: no flags array; k3 recomputes overflow from cnt (never taken).

#define VOCAB 100000
#define EMBED 256
#define NTOK  (32 * 2048)
#define TILEW 16                  // vocab cols per bin
#define NTILE (VOCAB / TILEW)     // 6250 bins
#define CAP   64                  // slots per bin (mean 10.5; P(>64) ~ 1e-40)
#define LSTRIDE 260               // floats; 1040 B rows: 16B-aligned, banks (4i+e)%32

// workspace ints: cnt [0,8192) | list [8192, 8192+NTILE*CAP)
#define WS_CNT_OFF   0
#define WS_LIST_OFF  8192
#define WS_INTS      (WS_LIST_OFF + NTILE * CAP)

__global__ __launch_bounds__(256) void k1_bucket(
    const int* __restrict__ x,
    int* __restrict__ cnt,
    int* __restrict__ list)
{
    int t4 = (blockIdx.x * 256 + threadIdx.x) * 4;
    if (t4 >= NTOK) return;
    const int4 v4 = *reinterpret_cast<const int4*>(x + t4);
    #pragma unroll
    for (int j = 0; j < 4; ++j) {
        const int v   = (&v4.x)[j];
        const int t   = t4 + j;
        const int bin = v >> 4;
        const int i   = v & 15;
        const int pos = atomicAdd(&cnt[bin], 1);
        if (pos < CAP) list[bin * CAP + pos] = t | (i << 16);
    }
}

__global__ __launch_bounds__(256) void k2_scatter(
    const float* __restrict__ W,
    const float* __restrict__ bias,
    const int* __restrict__ cnt,
    const int* __restrict__ list,
    float* __restrict__ out)
{
    // per-wave private tile: [i][e], i=0..15 vocab-in-bin, stride 260
    __shared__ float tile[4][TILEW * LSTRIDE];   // 4 x 16.6 KB = 66.6 KB

    const int wave = threadIdx.x >> 6;
    const int lane = threadIdx.x & 63;
    const int bin  = blockIdx.x * 4 + wave;
    if (bin >= NTILE) return;                    // wave-uniform exit

    const int v0 = bin << 4;
    float* T = tile[wave];

    // lane k holds list slot k (one coalesced 256 B load per wave)
    const int myent = list[bin * CAP + lane];
    int n = cnt[bin];                            // uniform -> scalar load
    if (n > CAP) n = CAP;

    // stage: 16 INDEPENDENT float4 loads back-to-back (16 KB in flight/wave),
    // instr j covers e = 16j..16j+15 (64 B per e-row island).
    const int eb = lane >> 2;                    // 0..15
    const int c4 = (lane & 3) << 2;              // 0,4,8,12
    float4 r[16];
    #pragma unroll
    for (int j = 0; j < 16; ++j)
        r[j] = *reinterpret_cast<const float4*>(
            W + (size_t)(16 * j + eb) * VOCAB + v0 + c4);

    // transpose into private LDS; banks (4(c4+k)+e)%32: 16(l&3)+(l>>2) is a
    // 0..63 bijection -> exact 2-way = free. No __syncthreads needed: only
    // this wave touches T, ds ordering via waitcnt.
    #pragma unroll
    for (int j = 0; j < 16; ++j) {
        const int e = 16 * j + eb;
        T[(c4 + 0) * LSTRIDE + e] = r[j].x;
        T[(c4 + 1) * LSTRIDE + e] = r[j].y;
        T[(c4 + 2) * LSTRIDE + e] = r[j].z;
        T[(c4 + 3) * LSTRIDE + e] = r[j].w;
    }

    const float4 bv = *reinterpret_cast<const float4*>(bias + lane * 4);

    for (int k = 0; k < n; ++k) {
        const int packed = __shfl(myent, k);
        const int tok = packed & 0xFFFF;
        const int i   = packed >> 16;
        // aligned ds_read_b128, banks start 4(i+l)%32 -> full rate
        const float4 s = *reinterpret_cast<const float4*>(&T[i * LSTRIDE + lane * 4]);
        float4 o;
        o.x = s.x + bv.x;  o.y = s.y + bv.y;
        o.z = s.z + bv.z;  o.w = s.w + bv.w;
        *reinterpret_cast<float4*>(out + (size_t)tok * EMBED + lane * 4) = o;
    }
}

__global__ __launch_bounds__(256) void k3_cleanup(
    const int* __restrict__ x,
    const float* __restrict__ W,
    const float* __restrict__ bias,
    const int* __restrict__ cnt,
    float* __restrict__ out)
{
    int t = blockIdx.x * 256 + threadIdx.x;
    if (t >= NTOK) return;
    int v = x[t];
    if (cnt[v >> 4] <= CAP) return;     // never taken for this input
    for (int e = 0; e < EMBED; ++e)
        out[(size_t)t * EMBED + e] = W[(size_t)e * VOCAB + v] + bias[e];
}

// fallback: direct column gather, if ws too small
__global__ __launch_bounds__(256) void embed_gather_direct(
    const int* __restrict__ x,
    const float* __restrict__ W,
    const float* __restrict__ bias,
    float* __restrict__ out)
{
    const int tid   = blockIdx.x * blockDim.x + threadIdx.x;
    const int token = tid >> 6;
    const int e     = (tid & 63) << 2;
    if (token >= NTOK) return;
    const int v = x[token];
    const float4 bv = *reinterpret_cast<const float4*>(bias + e);
    float4 r;
    r.x = W[(size_t)(e + 0) * VOCAB + v] + bv.x;
    r.y = W[(size_t)(e + 1) * VOCAB + v] + bv.y;
    r.z = W[(size_t)(e + 2) * VOCAB + v] + bv.z;
    r.w = W[(size_t)(e + 3) * VOCAB + v] + bv.w;
    *reinterpret_cast<float4*>(out + (size_t)token * EMBED + e) = r;
}

extern "C" void kernel_launch(void* const* d_in, const int* in_sizes, int n_in,
                              void* d_out, int out_size, void* d_ws, size_t ws_size,
                              hipStream_t stream)
{
    const int*   x = (const int*)d_in[0];
    const float* W = (const float*)d_in[1];
    const float* b = (const float*)d_in[2];
    float*     out = (float*)d_out;

    if (ws_size >= (size_t)WS_INTS * sizeof(int)) {
        int* ws   = (int*)d_ws;
        int* cnt  = ws + WS_CNT_OFF;
        int* list = ws + WS_LIST_OFF;

        hipMemsetAsync(cnt, 0, NTILE * sizeof(int), stream);
        k1_bucket <<<NTOK / 4 / 256,    256, 0, stream>>>(x, cnt, list);
        k2_scatter<<<(NTILE + 3) / 4,   256, 0, stream>>>(W, b, cnt, list, out);
        k3_cleanup<<<NTOK / 256,        256, 0, stream>>>(x, W, b, cnt, out);
    } else {
        embed_gather_direct<<<NTOK * 64 / 256, 256, 0, stream>>>(x, W, b, out);
    }
}